// Round 3
// baseline (3999.637 us; speedup 1.0000x reference)
//
#include <hip/hip_runtime.h>
#include <hip/hip_bf16.h>

typedef __hip_bfloat16 bf16;

#define NN 50000
#define EE 800000
#define RRR 8
#define DD 128
#define NDRUG 4000
#define PPAIR 8192

// ---------------- setup kernels ----------------

__global__ __launch_bounds__(256) void k_count(const int* __restrict__ ei,
                                               const int* __restrict__ et,
                                               int* __restrict__ cnt) {
    int e = blockIdx.x * 256 + threadIdx.x;
    if (e < EE) {
        int dst = ei[EE + e];
        atomicAdd(&cnt[dst * RRR + et[e]], 1);
    }
}

__global__ __launch_bounds__(256) void k_inv_indeg(const int* __restrict__ cnt,
                                                   float* __restrict__ inv,
                                                   int* __restrict__ indeg) {
    int n = blockIdx.x * 256 + threadIdx.x;
    if (n < NN) {
        int s = 0;
#pragma unroll
        for (int r = 0; r < RRR; r++) {
            int c = cnt[n * RRR + r];
            s += c;
            inv[n * RRR + r] = 1.0f / (float)(c > 0 ? c : 1);
        }
        indeg[n] = s;
    }
}

// single-block exclusive scan of indeg -> offs (and cursor copy)
__global__ __launch_bounds__(256) void k_scan_offsets(const int* __restrict__ indeg,
                                                      int* __restrict__ offs,
                                                      int* __restrict__ cursor) {
    __shared__ int buf[256];
    __shared__ int sbase;
    int tid = threadIdx.x;
    if (tid == 0) sbase = 0;
    __syncthreads();
    for (int c0 = 0; c0 < NN; c0 += 256) {
        int i = c0 + tid;
        int v = (i < NN) ? indeg[i] : 0;
        buf[tid] = v;
        __syncthreads();
        for (int s = 1; s < 256; s <<= 1) {
            int t = (tid >= s) ? buf[tid - s] : 0;
            __syncthreads();
            buf[tid] += t;
            __syncthreads();
        }
        int excl = sbase + buf[tid] - v;
        if (i < NN) { offs[i] = excl; cursor[i] = excl; }
        __syncthreads();
        if (tid == 255) sbase += buf[255];
        __syncthreads();
    }
    if (tid == 0) offs[NN] = sbase;
}

__global__ __launch_bounds__(256) void k_scatter(const int* __restrict__ ei,
                                                 const int* __restrict__ et,
                                                 int* __restrict__ cursor,
                                                 int* __restrict__ sorted) {
    int e = blockIdx.x * 256 + threadIdx.x;
    if (e < EE) {
        int dst = ei[EE + e];
        int pos = atomicAdd(&cursor[dst], 1);
        sorted[pos] = ei[e] | (et[e] << 20);
    }
}

// single-block scan: first NDRUG indices with node_type == 0 (ascending)
__global__ __launch_bounds__(256) void k_drug_select(const int* __restrict__ node_type,
                                                     int* __restrict__ didx) {
    __shared__ int buf[256];
    __shared__ int sbase;
    int tid = threadIdx.x;
    if (tid == 0) sbase = 0;
    __syncthreads();
    for (int c0 = 0; c0 < NN; c0 += 256) {
        int i = c0 + tid;
        int v = (i < NN && node_type[i] == 0) ? 1 : 0;
        buf[tid] = v;
        __syncthreads();
        for (int s = 1; s < 256; s <<= 1) {
            int t = (tid >= s) ? buf[tid - s] : 0;
            __syncthreads();
            buf[tid] += t;
            __syncthreads();
        }
        int excl = sbase + buf[tid] - v;
        if (v && excl < NDRUG) didx[excl] = i;
        __syncthreads();
        if (tid == 255) sbase += buf[255];
        __syncthreads();
    }
}

// ---------------- dense kernels ----------------

// T[r][n][e] = sum_d A[n][d] * W[r][d][e]   (bf16 out)
// grid (NN/16, 8), block 128
__global__ __launch_bounds__(128) void k_gemm_rel(const float* __restrict__ A,
                                                  const float* __restrict__ W,
                                                  bf16* __restrict__ T) {
    int r = blockIdx.y;
    int n0 = blockIdx.x * 16;
    int t = threadIdx.x;
    __shared__ float As[16][DD];
#pragma unroll
    for (int i = 0; i < 16; i++) As[i][t] = A[(size_t)(n0 + i) * DD + t];
    __syncthreads();
    const float* B = W + (size_t)r * DD * DD;
    float acc[16];
#pragma unroll
    for (int i = 0; i < 16; i++) acc[i] = 0.f;
#pragma unroll 4
    for (int k = 0; k < DD; k++) {
        float bv = B[k * DD + t];
#pragma unroll
        for (int i = 0; i < 16; i++) acc[i] += As[i][k] * bv;
    }
#pragma unroll
    for (int i = 0; i < 16; i++)
        T[((size_t)r * NN + n0 + i) * DD + t] = __float2bfloat16(acc[i]);
}

// C[m][e] = sum_d A[m][d]*B[d][e] + bias[e]; optional relu. grid(M/16), block 128
__global__ __launch_bounds__(128) void k_gemm_f32(const float* __restrict__ A,
                                                  const float* __restrict__ B,
                                                  const float* __restrict__ bias,
                                                  float* __restrict__ C,
                                                  int M, int relu) {
    int n0 = blockIdx.x * 16;
    int t = threadIdx.x;
    __shared__ float As[16][DD];
#pragma unroll
    for (int i = 0; i < 16; i++) {
        int row = n0 + i;
        As[i][t] = (row < M) ? A[(size_t)row * DD + t] : 0.f;
    }
    __syncthreads();
    float acc[16];
#pragma unroll
    for (int i = 0; i < 16; i++) acc[i] = 0.f;
#pragma unroll 4
    for (int k = 0; k < DD; k++) {
        float bv = B[k * DD + t];
#pragma unroll
        for (int i = 0; i < 16; i++) acc[i] += As[i][k] * bv;
    }
    float bs = bias[t];
#pragma unroll
    for (int i = 0; i < 16; i++) {
        int row = n0 + i;
        if (row < M) {
            float v = acc[i] + bs;
            if (relu) v = fmaxf(v, 0.f);
            C[(size_t)row * DD + t] = v;
        }
    }
}

// h[n] = relu(h[n] (root+bias part) + sum_{edges into n} T[et][src]/cnt[n,et])
// grid NN blocks, block 128
__global__ __launch_bounds__(128) void k_agg(const bf16* __restrict__ T,
                                             const float* __restrict__ inv,
                                             const int* __restrict__ offs,
                                             const int* __restrict__ sorted,
                                             float* __restrict__ h) {
    int n = blockIdx.x;
    int t = threadIdx.x;
    int s0 = offs[n], s1 = offs[n + 1];
    float acc = h[(size_t)n * DD + t];
    int k = s0;
    for (; k + 4 <= s1; k += 4) {
        int pk0 = sorted[k], pk1 = sorted[k + 1], pk2 = sorted[k + 2], pk3 = sorted[k + 3];
        int s_0 = pk0 & 0xFFFFF, e_0 = pk0 >> 20;
        int s_1 = pk1 & 0xFFFFF, e_1 = pk1 >> 20;
        int s_2 = pk2 & 0xFFFFF, e_2 = pk2 >> 20;
        int s_3 = pk3 & 0xFFFFF, e_3 = pk3 >> 20;
        float v0 = __bfloat162float(T[((size_t)e_0 * NN + s_0) * DD + t]);
        float v1 = __bfloat162float(T[((size_t)e_1 * NN + s_1) * DD + t]);
        float v2 = __bfloat162float(T[((size_t)e_2 * NN + s_2) * DD + t]);
        float v3 = __bfloat162float(T[((size_t)e_3 * NN + s_3) * DD + t]);
        acc += v0 * inv[n * RRR + e_0];
        acc += v1 * inv[n * RRR + e_1];
        acc += v2 * inv[n * RRR + e_2];
        acc += v3 * inv[n * RRR + e_3];
    }
    for (; k < s1; k++) {
        int pk = sorted[k];
        int src = pk & 0xFFFFF, et = pk >> 20;
        acc += __bfloat162float(T[((size_t)et * NN + src) * DD + t]) * inv[n * RRR + et];
    }
    h[(size_t)n * DD + t] = fmaxf(acc, 0.f);
}

// Wt[(i*128+j)*128 + o] = bilW[(o*128+i)*128 + j]
__global__ __launch_bounds__(256) void k_transpose_bil(const float* __restrict__ W,
                                                       float* __restrict__ Wt) {
    int idx = blockIdx.x * 256 + threadIdx.x;
    if (idx < DD * DD * DD) {
        int o = idx & 127;
        int j = (idx >> 7) & 127;
        int i = idx >> 14;
        Wt[idx] = W[((size_t)o * DD + i) * DD + j];
    }
}

// out[p][o] = relu( sum_ij fa[p][i]*fb[p][j]*W[o][i][j] + bb[o] )
// grid PPAIR/16 blocks, block 128 (thread = o)
__global__ __launch_bounds__(128) void k_bilinear(const float* __restrict__ h,
                                                  const int* __restrict__ didx,
                                                  const int* __restrict__ ef,
                                                  const float* __restrict__ Wt,
                                                  const float* __restrict__ bb,
                                                  float* __restrict__ out) {
    int p0 = blockIdx.x * 16;
    int o = threadIdx.x;
    __shared__ float fa[16][DD];
    __shared__ float fb[16][DD];
    __shared__ float z[16][DD];
#pragma unroll
    for (int i = 0; i < 16; i++) {
        int p = p0 + i;
        int na = didx[ef[p]];
        int nb = didx[ef[PPAIR + p]];
        fa[i][o] = h[(size_t)na * DD + o];
        fb[i][o] = h[(size_t)nb * DD + o];
    }
    __syncthreads();
    float acc[16];
#pragma unroll
    for (int i = 0; i < 16; i++) acc[i] = 0.f;
    for (int i = 0; i < DD; i++) {
#pragma unroll
        for (int pp = 0; pp < 16; pp++) z[pp][o] = fa[pp][i] * fb[pp][o];
        __syncthreads();
#pragma unroll 2
        for (int j = 0; j < DD; j++) {
            float bv = Wt[((size_t)i * DD + j) * DD + o];
#pragma unroll
            for (int pp = 0; pp < 16; pp++) acc[pp] += z[pp][j] * bv;
        }
        __syncthreads();
    }
    float bias = bb[o];
#pragma unroll
    for (int pp = 0; pp < 16; pp++)
        out[(size_t)(p0 + pp) * DD + o] = fmaxf(acc[pp] + bias, 0.f);
}

// ---------------- launch ----------------

extern "C" void kernel_launch(void* const* d_in, const int* in_sizes, int n_in,
                              void* d_out, int out_size, void* d_ws, size_t ws_size,
                              hipStream_t stream) {
    const float* x      = (const float*)d_in[0];
    const int*   ei     = (const int*)d_in[1];
    const int*   et     = (const int*)d_in[2];
    const int*   ntype  = (const int*)d_in[3];
    const int*   efil   = (const int*)d_in[4];
    const float* W1 = (const float*)d_in[5];
    const float* r1 = (const float*)d_in[6];
    const float* b1 = (const float*)d_in[7];
    const float* W2 = (const float*)d_in[8];
    const float* r2 = (const float*)d_in[9];
    const float* b2 = (const float*)d_in[10];
    const float* W3 = (const float*)d_in[11];
    const float* r3 = (const float*)d_in[12];
    const float* b3 = (const float*)d_in[13];
    const float* bilW = (const float*)d_in[14];
    const float* bilb = (const float*)d_in[15];
    const float* m1W = (const float*)d_in[16];
    const float* m1b = (const float*)d_in[17];
    const float* m2W = (const float*)d_in[18];
    const float* m2b = (const float*)d_in[19];
    const float* m3W = (const float*)d_in[20];
    const float* m3b = (const float*)d_in[21];
    float* outp = (float*)d_out;

    char* ws = (char*)d_ws;
    size_t off = 0;
    auto alloc = [&](size_t bytes) { size_t c = off; off = (off + bytes + 255) & ~(size_t)255; return c; };

    size_t oT     = alloc((size_t)RRR * NN * DD * sizeof(bf16));   // 102.4 MB
    size_t ohA    = alloc((size_t)NN * DD * sizeof(float));        // 25.6 MB
    size_t ohB    = alloc((size_t)NN * DD * sizeof(float));        // 25.6 MB
    size_t ocnt   = alloc((size_t)NN * RRR * sizeof(int));
    size_t oinv   = alloc((size_t)NN * RRR * sizeof(float));
    size_t oindeg = alloc((size_t)NN * sizeof(int));
    size_t ooffs  = alloc((size_t)(NN + 1) * sizeof(int));
    size_t ocur   = alloc((size_t)NN * sizeof(int));
    size_t osort  = alloc((size_t)EE * sizeof(int));
    size_t odidx  = alloc((size_t)NDRUG * sizeof(int));

    bf16*  T      = (bf16*)(ws + oT);
    float* hA     = (float*)(ws + ohA);
    float* hB     = (float*)(ws + ohB);
    int*   cnt    = (int*)(ws + ocnt);
    float* inv    = (float*)(ws + oinv);
    int*   indeg  = (int*)(ws + oindeg);
    int*   offs   = (int*)(ws + ooffs);
    int*   cursor = (int*)(ws + ocur);
    int*   sorted = (int*)(ws + osort);
    int*   didx   = (int*)(ws + odidx);

    // dead after layer-3 aggregation: alias pair buffers into T region
    float* Wt   = (float*)(ws + oT);                        // 8.39 MB
    float* xab  = (float*)(ws + oT + (16u << 20));          // 4.19 MB
    float* xab2 = (float*)(ws + oT + (24u << 20));          // 4.19 MB

    hipMemsetAsync(cnt, 0, (size_t)NN * RRR * sizeof(int), stream);
    hipMemsetAsync(didx, 0, (size_t)NDRUG * sizeof(int), stream);

    k_count<<<(EE + 255) / 256, 256, 0, stream>>>(ei, et, cnt);
    k_inv_indeg<<<(NN + 255) / 256, 256, 0, stream>>>(cnt, inv, indeg);
    k_scan_offsets<<<1, 256, 0, stream>>>(indeg, offs, cursor);
    k_scatter<<<(EE + 255) / 256, 256, 0, stream>>>(ei, et, cursor, sorted);
    k_drug_select<<<1, 256, 0, stream>>>(ntype, didx);

    dim3 grel(NN / 16, RRR);

    // layer 1: x -> hA
    k_gemm_rel<<<grel, 128, 0, stream>>>(x, W1, T);
    k_gemm_f32<<<NN / 16, 128, 0, stream>>>(x, r1, b1, hA, NN, 0);
    k_agg<<<NN, 128, 0, stream>>>(T, inv, offs, sorted, hA);

    // layer 2: hA -> hB
    k_gemm_rel<<<grel, 128, 0, stream>>>(hA, W2, T);
    k_gemm_f32<<<NN / 16, 128, 0, stream>>>(hA, r2, b2, hB, NN, 0);
    k_agg<<<NN, 128, 0, stream>>>(T, inv, offs, sorted, hB);

    // layer 3: hB -> hA
    k_gemm_rel<<<grel, 128, 0, stream>>>(hB, W3, T);
    k_gemm_f32<<<NN / 16, 128, 0, stream>>>(hB, r3, b3, hA, NN, 0);
    k_agg<<<NN, 128, 0, stream>>>(T, inv, offs, sorted, hA);

    // pair head (T region now dead -> reuse for Wt/xab)
    k_transpose_bil<<<(DD * DD * DD + 255) / 256, 256, 0, stream>>>(bilW, Wt);
    k_bilinear<<<PPAIR / 16, 128, 0, stream>>>(hA, didx, efil, Wt, bilb, xab);
    k_gemm_f32<<<PPAIR / 16, 128, 0, stream>>>(xab, m1W, m1b, xab2, PPAIR, 1);
    k_gemm_f32<<<PPAIR / 16, 128, 0, stream>>>(xab2, m2W, m2b, xab, PPAIR, 1);
    k_gemm_f32<<<PPAIR / 16, 128, 0, stream>>>(xab, m3W, m3b, outp, PPAIR, 0);
}

// Round 4
// 900.262 us; speedup vs baseline: 4.4427x; 4.4427x over previous
//
#include <hip/hip_runtime.h>
#include <hip/hip_bf16.h>

typedef unsigned short ushort_t;
typedef __attribute__((ext_vector_type(8))) short short8v;
typedef __attribute__((ext_vector_type(4))) float f32x4;
typedef __attribute__((ext_vector_type(4))) int int4v;

#define NN 50000
#define EE 800000
#define RRR 8
#define DD 128
#define NDRUG 4000
#define PPAIR 8192

__device__ __forceinline__ float bf2f(ushort_t u) {
    unsigned int v = ((unsigned int)u) << 16;
    float f; __builtin_memcpy(&f, &v, 4); return f;
}
__device__ __forceinline__ ushort_t f2bf(float f) {
    unsigned int b; __builtin_memcpy(&b, &f, 4);
    unsigned int r = (b + 0x7FFFu + ((b >> 16) & 1u)) >> 16;
    return (ushort_t)r;
}

// ---------------- setup kernels ----------------

__global__ __launch_bounds__(256) void k_count(const int* __restrict__ ei,
                                               const int* __restrict__ et,
                                               int* __restrict__ cnt) {
    int e = blockIdx.x * 256 + threadIdx.x;
    if (e < EE) {
        int dst = ei[EE + e];
        atomicAdd(&cnt[dst * RRR + et[e]], 1);
    }
}

__global__ __launch_bounds__(256) void k_inv_indeg(const int* __restrict__ cnt,
                                                   float* __restrict__ inv,
                                                   int* __restrict__ indeg) {
    int n = blockIdx.x * 256 + threadIdx.x;
    if (n < NN) {
        int s = 0;
#pragma unroll
        for (int r = 0; r < RRR; r++) {
            int c = cnt[n * RRR + r];
            s += c;
            inv[n * RRR + r] = 1.0f / (float)(c > 0 ? c : 1);
        }
        indeg[n] = s;
    }
}

// shfl-based single-block exclusive scan (1024 threads)
__global__ __launch_bounds__(1024) void k_scan2(const int* __restrict__ indeg,
                                                int* __restrict__ offs,
                                                int* __restrict__ cursor) {
    __shared__ int ws[16];
    __shared__ int sbase;
    int tid = threadIdx.x, wid = tid >> 6, lane = tid & 63;
    if (tid == 0) sbase = 0;
    __syncthreads();
    for (int c0 = 0; c0 < NN; c0 += 1024) {
        int i = c0 + tid;
        int v0 = (i < NN) ? indeg[i] : 0;
        int v = v0;
#pragma unroll
        for (int off = 1; off < 64; off <<= 1) {
            int u = __shfl_up(v, off);
            if (lane >= off) v += u;
        }
        if (lane == 63) ws[wid] = v;
        __syncthreads();
        if (wid == 0) {
            int wv = (lane < 16) ? ws[lane] : 0;
#pragma unroll
            for (int off = 1; off < 16; off <<= 1) {
                int u = __shfl_up(wv, off);
                if (lane >= off) wv += u;
            }
            if (lane < 16) ws[lane] = wv;
        }
        __syncthreads();
        int excl = sbase + (wid ? ws[wid - 1] : 0) + (v - v0);
        if (i < NN) { offs[i] = excl; cursor[i] = excl; }
        __syncthreads();
        if (tid == 0) sbase += ws[15];
        __syncthreads();
    }
    if (threadIdx.x == 0) offs[NN] = sbase;
}

__global__ __launch_bounds__(1024) void k_select2(const int* __restrict__ ntype,
                                                  int* __restrict__ didx) {
    __shared__ int ws[16];
    __shared__ int sbase;
    int tid = threadIdx.x, wid = tid >> 6, lane = tid & 63;
    if (tid == 0) sbase = 0;
    __syncthreads();
    for (int c0 = 0; c0 < NN; c0 += 1024) {
        int i = c0 + tid;
        int v0 = (i < NN && ntype[i] == 0) ? 1 : 0;
        int v = v0;
#pragma unroll
        for (int off = 1; off < 64; off <<= 1) {
            int u = __shfl_up(v, off);
            if (lane >= off) v += u;
        }
        if (lane == 63) ws[wid] = v;
        __syncthreads();
        if (wid == 0) {
            int wv = (lane < 16) ? ws[lane] : 0;
#pragma unroll
            for (int off = 1; off < 16; off <<= 1) {
                int u = __shfl_up(wv, off);
                if (lane >= off) wv += u;
            }
            if (lane < 16) ws[lane] = wv;
        }
        __syncthreads();
        int excl = sbase + (wid ? ws[wid - 1] : 0) + (v - v0);
        if (v0 && excl < NDRUG) didx[excl] = i;
        __syncthreads();
        if (tid == 0) sbase += ws[15];
        __syncthreads();
    }
}

__global__ __launch_bounds__(256) void k_scatter(const int* __restrict__ ei,
                                                 const int* __restrict__ et,
                                                 int* __restrict__ cursor,
                                                 int* __restrict__ sorted) {
    int e = blockIdx.x * 256 + threadIdx.x;
    if (e < EE) {
        int dst = ei[EE + e];
        int pos = atomicAdd(&cursor[dst], 1);
        sorted[pos] = ei[e] | (et[e] << 20);
    }
}

// ---------------- prep kernels ----------------

// f32 -> bf16, 4 elems/thread
__global__ __launch_bounds__(256) void k_cvt(const float* __restrict__ src,
                                             ushort_t* __restrict__ dst, int n4) {
    int i = blockIdx.x * 256 + threadIdx.x;
    if (i < n4) {
        float4 v = ((const float4*)src)[i];
        uint2 o;
        o.x = (unsigned int)f2bf(v.x) | ((unsigned int)f2bf(v.y) << 16);
        o.y = (unsigned int)f2bf(v.z) | ((unsigned int)f2bf(v.w) << 16);
        ((uint2*)dst)[i] = o;
    }
}

// Wt[slab][col][kk] = bf16( src[kk][col] ), src = W8[slab] (slab<8) else root
__global__ __launch_bounds__(256) void k_prep_w(const float* __restrict__ W8,
                                                const float* __restrict__ root,
                                                ushort_t* __restrict__ dst, int total) {
    int idx = blockIdx.x * 256 + threadIdx.x;
    if (idx < total) {
        int slab = idx >> 14, rem = idx & 16383, col = rem >> 7, kk = rem & 127;
        const float* src = (W8 != nullptr && slab < 8) ? (W8 + slab * 16384) : root;
        dst[idx] = f2bf(src[kk * 128 + col]);
    }
}

// ---------------- MFMA GEMM: C[slab] = act(A @ Wt[slab] + bias) ----------------
// A: bf16 [M][128]; Wt: bf16 [slabs][col(128)][kk(128)]; out: bf16 or f32 [slab*M + row][128]
// block 256 thr = 4 waves (16 rows each), BM=64, N=128, K=128
__global__ __launch_bounds__(256) void k_mfma_nn(const ushort_t* __restrict__ A,
                                                 const ushort_t* __restrict__ Wt,
                                                 const float* __restrict__ bias,
                                                 ushort_t* __restrict__ outb,
                                                 float* __restrict__ outf,
                                                 int M, int nMblk, int relu) {
    __shared__ short As[64 * 136];
    __shared__ short Bs[128 * 136];
    int tid = threadIdx.x;
    int slab = blockIdx.x / nMblk;
    int mblk = blockIdx.x % nMblk;
    int row0 = mblk * 64;

    // stage A (64x128 bf16, pad to 136)
    const int4v* Ag = (const int4v*)A;
    int4v* AsV = (int4v*)As;
    for (int idx = tid; idx < 1024; idx += 256) {
        int row = idx >> 4, ck = idx & 15;
        int grow = row0 + row;
        int4v v = {0, 0, 0, 0};
        if (grow < M) v = Ag[(size_t)grow * 16 + ck];
        AsV[row * 17 + ck] = v;
    }
    // stage B (slab's 128x128 bf16, already [col][kk])
    const int4v* Wg = (const int4v*)Wt + (size_t)slab * 2048;
    int4v* BsV = (int4v*)Bs;
    for (int idx = tid; idx < 2048; idx += 256) {
        int col = idx >> 4, ck = idx & 15;
        BsV[col * 17 + ck] = Wg[idx];
    }
    __syncthreads();

    int wid = tid >> 6, lane = tid & 63, lo = lane & 15, hi = lane >> 4;
    int wrow0 = wid * 16;
    f32x4 acc[8];
#pragma unroll
    for (int t = 0; t < 8; t++) acc[t] = (f32x4)(0.f);

#pragma unroll
    for (int s = 0; s < 4; ++s) {
        short8v a = *(const short8v*)&As[(wrow0 + lo) * 136 + s * 32 + hi * 8];
#pragma unroll
        for (int t = 0; t < 8; t++) {
            short8v b = *(const short8v*)&Bs[(t * 16 + lo) * 136 + s * 32 + hi * 8];
            acc[t] = __builtin_amdgcn_mfma_f32_16x16x32_bf16(a, b, acc[t], 0, 0, 0);
        }
    }

#pragma unroll
    for (int t = 0; t < 8; t++) {
        int col = t * 16 + lo;
        float bs = bias ? bias[col] : 0.f;
#pragma unroll
        for (int q = 0; q < 4; q++) {
            int grow = row0 + wrow0 + hi * 4 + q;
            if (grow < M) {
                float v = acc[t][q] + bs;
                if (relu) v = fmaxf(v, 0.f);
                size_t oidx = ((size_t)slab * M + grow) * 128 + col;
                if (outb) outb[oidx] = f2bf(v);
                else      outf[oidx] = v;
            }
        }
    }
}

// ---------------- aggregation ----------------
// hb[n] = relu(bias + T[8][n] + sum_edges T[et][src] * inv[n,et])
__global__ __launch_bounds__(128) void k_agg2(const ushort_t* __restrict__ T,
                                              const float* __restrict__ inv,
                                              const int* __restrict__ offs,
                                              const int* __restrict__ sorted,
                                              const float* __restrict__ bias,
                                              ushort_t* __restrict__ hb) {
    int n = blockIdx.x;
    int t = threadIdx.x;
    int s0 = offs[n], s1 = offs[n + 1];
    float acc = bias[t] + bf2f(T[((size_t)8 * NN + n) * 128 + t]);
    int k = s0;
    for (; k + 4 <= s1; k += 4) {
        int pk0 = sorted[k], pk1 = sorted[k + 1], pk2 = sorted[k + 2], pk3 = sorted[k + 3];
        int s_0 = pk0 & 0xFFFFF, e_0 = pk0 >> 20;
        int s_1 = pk1 & 0xFFFFF, e_1 = pk1 >> 20;
        int s_2 = pk2 & 0xFFFFF, e_2 = pk2 >> 20;
        int s_3 = pk3 & 0xFFFFF, e_3 = pk3 >> 20;
        float v0 = bf2f(T[((size_t)e_0 * NN + s_0) * 128 + t]);
        float v1 = bf2f(T[((size_t)e_1 * NN + s_1) * 128 + t]);
        float v2 = bf2f(T[((size_t)e_2 * NN + s_2) * 128 + t]);
        float v3 = bf2f(T[((size_t)e_3 * NN + s_3) * 128 + t]);
        acc += v0 * inv[n * RRR + e_0];
        acc += v1 * inv[n * RRR + e_1];
        acc += v2 * inv[n * RRR + e_2];
        acc += v3 * inv[n * RRR + e_3];
    }
    for (; k < s1; k++) {
        int pk = sorted[k];
        int src = pk & 0xFFFFF, et = pk >> 20;
        acc += bf2f(T[((size_t)et * NN + src) * 128 + t]) * inv[n * RRR + et];
    }
    hb[(size_t)n * 128 + t] = f2bf(fmaxf(acc, 0.f));
}

// ---------------- bilinear: MFMA with on-the-fly rank-1 A ----------------
// out[p][o] = relu( sum_kk Z[p][kk] * Wb[o][kk] + bb[o] ), Z[p][i*128+j]=fa[p][i]*fb[p][j]
// block: 512 thr = 8 waves; 32 pairs/block; wave w handles K-chunk [w*2048, (w+1)*2048)
__global__ __launch_bounds__(512) void k_bil(const ushort_t* __restrict__ hb,
                                             const int* __restrict__ didx,
                                             const int* __restrict__ efil,
                                             const ushort_t* __restrict__ Wb,
                                             const float* __restrict__ bilb,
                                             ushort_t* __restrict__ xab) {
    __shared__ __align__(16) char smem[65536];
    __shared__ int pa[32], pb[32];
    float* faT = (float*)smem;             // [i:128][p:32]
    float* fbF = (float*)(smem + 16384);   // [p:32][j:132]
    int tid = threadIdx.x;
    int p0 = blockIdx.x * 32;

    if (tid < 32) pa[tid] = didx[efil[p0 + tid]];
    else if (tid < 64) pb[tid - 32] = didx[efil[PPAIR + p0 + tid - 32]];
    __syncthreads();

    // stage fa (transposed) and fb (padded): 512 threads, one chunk each
    {
        int p = tid >> 4, c8 = tid & 15;
        const int4v* hg = (const int4v*)hb;
        union { int4v v; short s[8]; } ra, rb;
        ra.v = hg[(size_t)pa[p] * 16 + c8];
        rb.v = hg[(size_t)pb[p] * 16 + c8];
        float4* fb4 = (float4*)fbF;
        float4 f0, f1;
        f0.x = bf2f((ushort_t)rb.s[0]); f0.y = bf2f((ushort_t)rb.s[1]);
        f0.z = bf2f((ushort_t)rb.s[2]); f0.w = bf2f((ushort_t)rb.s[3]);
        f1.x = bf2f((ushort_t)rb.s[4]); f1.y = bf2f((ushort_t)rb.s[5]);
        f1.z = bf2f((ushort_t)rb.s[6]); f1.w = bf2f((ushort_t)rb.s[7]);
        fb4[p * 33 + c8 * 2] = f0;
        fb4[p * 33 + c8 * 2 + 1] = f1;
#pragma unroll
        for (int j = 0; j < 8; j++)
            faT[(c8 * 8 + j) * 32 + p] = bf2f((ushort_t)ra.s[j]);
    }
    __syncthreads();

    int wid = tid >> 6, lane = tid & 63, lo = lane & 15, hi = lane >> 4;
    const int4v* Wbg = (const int4v*)Wb;
    const float4* fb4 = (const float4*)fbF;

    f32x4 acc0[8], acc1[8];
#pragma unroll
    for (int t = 0; t < 8; t++) { acc0[t] = (f32x4)(0.f); acc1[t] = (f32x4)(0.f); }

    for (int s = 0; s < 64; ++s) {
        int4v braw[8];
#pragma unroll
        for (int t = 0; t < 8; t++)
            braw[t] = Wbg[(t * 16 + lo) * 2048 + (wid << 8) + (s << 2) + hi];

        int i = (wid << 4) + (s >> 2);
        int jc4 = ((s & 3) << 3) + (hi << 1);
        short8v afr0, afr1;
#pragma unroll
        for (int mi = 0; mi < 2; ++mi) {
            int prow = (mi << 4) + lo;
            float fa = faT[i * 32 + prow];
            float4 f0 = fb4[prow * 33 + jc4];
            float4 f1 = fb4[prow * 33 + jc4 + 1];
            unsigned int u0, u1, u2, u3;
            asm("v_cvt_pk_bf16_f32 %0, %1, %2" : "=v"(u0) : "v"(fa * f0.x), "v"(fa * f0.y));
            asm("v_cvt_pk_bf16_f32 %0, %1, %2" : "=v"(u1) : "v"(fa * f0.z), "v"(fa * f0.w));
            asm("v_cvt_pk_bf16_f32 %0, %1, %2" : "=v"(u2) : "v"(fa * f1.x), "v"(fa * f1.y));
            asm("v_cvt_pk_bf16_f32 %0, %1, %2" : "=v"(u3) : "v"(fa * f1.z), "v"(fa * f1.w));
            union { unsigned int u[4]; short8v v; } cv;
            cv.u[0] = u0; cv.u[1] = u1; cv.u[2] = u2; cv.u[3] = u3;
            if (mi == 0) afr0 = cv.v; else afr1 = cv.v;
        }
#pragma unroll
        for (int t = 0; t < 8; t++) {
            union { int4v i4; short8v s8; } bb; bb.i4 = braw[t];
            acc0[t] = __builtin_amdgcn_mfma_f32_16x16x32_bf16(afr0, bb.s8, acc0[t], 0, 0, 0);
            acc1[t] = __builtin_amdgcn_mfma_f32_16x16x32_bf16(afr1, bb.s8, acc1[t], 0, 0, 0);
        }
    }
    __syncthreads();   // fa/fb dead; smem becomes reduce buffer red[4][32][128]

    float* redF = (float*)smem;
    if (wid >= 4) {
        float* r = redF + (wid - 4) * 4096;
#pragma unroll
        for (int t = 0; t < 8; t++)
#pragma unroll
            for (int q = 0; q < 4; q++) {
                r[(hi * 4 + q) * 128 + t * 16 + lo] = acc0[t][q];
                r[(16 + hi * 4 + q) * 128 + t * 16 + lo] = acc1[t][q];
            }
    }
    __syncthreads();
    if (wid < 4) {
        float* r = redF + wid * 4096;
#pragma unroll
        for (int t = 0; t < 8; t++)
#pragma unroll
            for (int q = 0; q < 4; q++) {
                acc0[t][q] += r[(hi * 4 + q) * 128 + t * 16 + lo];
                acc1[t][q] += r[(16 + hi * 4 + q) * 128 + t * 16 + lo];
            }
    }
    __syncthreads();
    if (wid < 4) {
        float* r = redF + wid * 4096;
#pragma unroll
        for (int t = 0; t < 8; t++)
#pragma unroll
            for (int q = 0; q < 4; q++) {
                r[(hi * 4 + q) * 128 + t * 16 + lo] = acc0[t][q];
                r[(16 + hi * 4 + q) * 128 + t * 16 + lo] = acc1[t][q];
            }
    }
    __syncthreads();
    for (int idx = tid; idx < 4096; idx += 512) {
        float s = redF[idx] + redF[4096 + idx] + redF[8192 + idx] + redF[12288 + idx]
                + bilb[idx & 127];
        s = fmaxf(s, 0.f);
        xab[(size_t)(p0 + (idx >> 7)) * 128 + (idx & 127)] = f2bf(s);
    }
}

// ---------------- launch ----------------

extern "C" void kernel_launch(void* const* d_in, const int* in_sizes, int n_in,
                              void* d_out, int out_size, void* d_ws, size_t ws_size,
                              hipStream_t stream) {
    const float* x      = (const float*)d_in[0];
    const int*   ei     = (const int*)d_in[1];
    const int*   et     = (const int*)d_in[2];
    const int*   ntype  = (const int*)d_in[3];
    const int*   efil   = (const int*)d_in[4];
    const float* W1 = (const float*)d_in[5];
    const float* r1 = (const float*)d_in[6];
    const float* b1 = (const float*)d_in[7];
    const float* W2 = (const float*)d_in[8];
    const float* r2 = (const float*)d_in[9];
    const float* b2 = (const float*)d_in[10];
    const float* W3 = (const float*)d_in[11];
    const float* r3 = (const float*)d_in[12];
    const float* b3 = (const float*)d_in[13];
    const float* bilW = (const float*)d_in[14];
    const float* bilb = (const float*)d_in[15];
    const float* m1W = (const float*)d_in[16];
    const float* m1b = (const float*)d_in[17];
    const float* m2W = (const float*)d_in[18];
    const float* m2b = (const float*)d_in[19];
    const float* m3W = (const float*)d_in[20];
    const float* m3b = (const float*)d_in[21];
    float* outp = (float*)d_out;

    char* ws = (char*)d_ws;
    size_t off = 0;
    auto alloc = [&](size_t bytes) { size_t c = off; off = (off + bytes + 255) & ~(size_t)255; return c; };

    size_t oT    = alloc((size_t)9 * NN * 128 * 2);   // 115.2 MB (T; later Wb/xab alias)
    size_t oxb   = alloc((size_t)NN * 128 * 2);       // xb; hbB aliases (xb dead after L1 gemm)
    size_t ohA   = alloc((size_t)NN * 128 * 2);
    size_t oWt1  = alloc((size_t)9 * 16384 * 2);
    size_t oWt2  = alloc((size_t)9 * 16384 * 2);
    size_t oWt3  = alloc((size_t)9 * 16384 * 2);
    size_t omW1  = alloc((size_t)16384 * 2);
    size_t omW2  = alloc((size_t)16384 * 2);
    size_t omW3  = alloc((size_t)16384 * 2);
    size_t ocnt  = alloc((size_t)NN * RRR * sizeof(int));
    size_t oinv  = alloc((size_t)NN * RRR * sizeof(float));
    size_t oindeg = alloc((size_t)NN * sizeof(int));
    size_t ooffs = alloc((size_t)(NN + 1) * sizeof(int));
    size_t ocur  = alloc((size_t)NN * sizeof(int));
    size_t osort = alloc((size_t)EE * sizeof(int));
    size_t odidx = alloc((size_t)NDRUG * sizeof(int));

    ushort_t* T    = (ushort_t*)(ws + oT);
    ushort_t* xb   = (ushort_t*)(ws + oxb);
    ushort_t* hbA  = (ushort_t*)(ws + ohA);
    ushort_t* hbB  = xb;                                // alias: xb dead after L1 GEMM
    ushort_t* Wt1  = (ushort_t*)(ws + oWt1);
    ushort_t* Wt2  = (ushort_t*)(ws + oWt2);
    ushort_t* Wt3  = (ushort_t*)(ws + oWt3);
    ushort_t* mWt1 = (ushort_t*)(ws + omW1);
    ushort_t* mWt2 = (ushort_t*)(ws + omW2);
    ushort_t* mWt3 = (ushort_t*)(ws + omW3);
    int*      cnt  = (int*)(ws + ocnt);
    float*    inv  = (float*)(ws + oinv);
    int*      indeg = (int*)(ws + oindeg);
    int*      offs = (int*)(ws + ooffs);
    int*      cursor = (int*)(ws + ocur);
    int*      sorted = (int*)(ws + osort);
    int*      didx = (int*)(ws + odidx);

    // T region dead after layer-3 agg: alias pair-head buffers into it
    ushort_t* Wb   = (ushort_t*)(ws + oT);                        // 4.19 MB
    ushort_t* xab1 = (ushort_t*)(ws + oT + ((size_t)8 << 20));    // 2 MB
    ushort_t* xab2 = (ushort_t*)(ws + oT + ((size_t)12 << 20));   // 2 MB

    hipMemsetAsync(cnt, 0, (size_t)NN * RRR * sizeof(int), stream);
    hipMemsetAsync(didx, 0, (size_t)NDRUG * sizeof(int), stream);

    // prep
    k_cvt<<<(NN * 128 / 4 + 255) / 256, 256, 0, stream>>>(x, xb, NN * 128 / 4);
    k_prep_w<<<(9 * 16384 + 255) / 256, 256, 0, stream>>>(W1, r1, Wt1, 9 * 16384);
    k_prep_w<<<(9 * 16384 + 255) / 256, 256, 0, stream>>>(W2, r2, Wt2, 9 * 16384);
    k_prep_w<<<(9 * 16384 + 255) / 256, 256, 0, stream>>>(W3, r3, Wt3, 9 * 16384);
    k_prep_w<<<(16384 + 255) / 256, 256, 0, stream>>>(nullptr, m1W, mWt1, 16384);
    k_prep_w<<<(16384 + 255) / 256, 256, 0, stream>>>(nullptr, m2W, mWt2, 16384);
    k_prep_w<<<(16384 + 255) / 256, 256, 0, stream>>>(nullptr, m3W, mWt3, 16384);

    // graph setup
    k_count<<<(EE + 255) / 256, 256, 0, stream>>>(ei, et, cnt);
    k_inv_indeg<<<(NN + 255) / 256, 256, 0, stream>>>(cnt, inv, indeg);
    k_scan2<<<1, 1024, 0, stream>>>(indeg, offs, cursor);
    k_scatter<<<(EE + 255) / 256, 256, 0, stream>>>(ei, et, cursor, sorted);
    k_select2<<<1, 1024, 0, stream>>>(ntype, didx);

    const int nMblkN = (NN + 63) / 64;   // 782
    const int nMblkP = PPAIR / 64;       // 128

    // layer 1
    k_mfma_nn<<<nMblkN * 9, 256, 0, stream>>>(xb, Wt1, nullptr, T, nullptr, NN, nMblkN, 0);
    k_agg2<<<NN, 128, 0, stream>>>(T, inv, offs, sorted, b1, hbA);
    // layer 2
    k_mfma_nn<<<nMblkN * 9, 256, 0, stream>>>(hbA, Wt2, nullptr, T, nullptr, NN, nMblkN, 0);
    k_agg2<<<NN, 128, 0, stream>>>(T, inv, offs, sorted, b2, hbB);
    // layer 3
    k_mfma_nn<<<nMblkN * 9, 256, 0, stream>>>(hbB, Wt3, nullptr, T, nullptr, NN, nMblkN, 0);
    k_agg2<<<NN, 128, 0, stream>>>(T, inv, offs, sorted, b3, hbA);

    // pair head (T dead -> Wb/xab alias)
    k_cvt<<<(2097152 / 4 + 255) / 256, 256, 0, stream>>>(bilW, Wb, 2097152 / 4);
    k_bil<<<PPAIR / 32, 512, 0, stream>>>(hbA, didx, efil, Wb, bilb, xab1);
    k_mfma_nn<<<nMblkP, 256, 0, stream>>>(xab1, mWt1, m1b, xab2, nullptr, PPAIR, nMblkP, 1);
    k_mfma_nn<<<nMblkP, 256, 0, stream>>>(xab2, mWt2, m2b, xab1, nullptr, PPAIR, nMblkP, 1);
    k_mfma_nn<<<nMblkP, 256, 0, stream>>>(xab1, mWt3, m3b, nullptr, outp, PPAIR, nMblkP, 0);
}

// Round 7
// 728.850 us; speedup vs baseline: 5.4876x; 1.2352x over previous
//
#include <hip/hip_runtime.h>
#include <hip/hip_bf16.h>

typedef unsigned short ushort_t;
typedef __attribute__((ext_vector_type(8))) short short8v;
typedef __attribute__((ext_vector_type(4))) float f32x4;
typedef __attribute__((ext_vector_type(4))) int int4v;

#define NN 50000
#define EE 800000
#define RRR 8
#define DD 128
#define NDRUG 4000
#define PPAIR 8192
#define BML 32
#define AFS 1160   // Af row stride in shorts (1152 + 8 pad -> 2-way banks only)

__device__ __forceinline__ float bf2f(ushort_t u) {
    unsigned int v = ((unsigned int)u) << 16;
    float f; __builtin_memcpy(&f, &v, 4); return f;
}
__device__ __forceinline__ ushort_t f2bf(float f) {
    unsigned int b; __builtin_memcpy(&b, &f, 4);
    unsigned int r = (b + 0x7FFFu + ((b >> 16) & 1u)) >> 16;
    return (ushort_t)r;
}
__device__ __forceinline__ unsigned int pkbf(float lo, float hi) {
    unsigned int r;
    asm("v_cvt_pk_bf16_f32 %0, %1, %2" : "=v"(r) : "v"(lo), "v"(hi));
    return r;
}

// ---------------- setup kernels ----------------

__global__ __launch_bounds__(256) void k_count(const int* __restrict__ ei,
                                               const int* __restrict__ et,
                                               int* __restrict__ cnt) {
    int e = blockIdx.x * 256 + threadIdx.x;
    if (e < EE) {
        int dst = ei[EE + e];
        atomicAdd(&cnt[dst * RRR + et[e]], 1);
    }
}

__global__ __launch_bounds__(256) void k_inv_indeg(const int* __restrict__ cnt,
                                                   float* __restrict__ inv,
                                                   int* __restrict__ indeg) {
    int n = blockIdx.x * 256 + threadIdx.x;
    if (n < NN) {
        int s = 0;
#pragma unroll
        for (int r = 0; r < RRR; r++) {
            int c = cnt[n * RRR + r];
            s += c;
            inv[n * RRR + r] = 1.0f / (float)(c > 0 ? c : 1);
        }
        indeg[n] = s;
    }
}

// merged: exclusive scan of indeg -> offs/cursor  AND  drug-select scan (shared barriers)
__global__ __launch_bounds__(1024) void k_scan_sel(const int* __restrict__ indeg,
                                                   const int* __restrict__ ntype,
                                                   int* __restrict__ offs,
                                                   int* __restrict__ cursor,
                                                   int* __restrict__ didx) {
    __shared__ int w1[16], w2[16];
    __shared__ int sb1, sb2;
    int tid = threadIdx.x, wid = tid >> 6, lane = tid & 63;
    if (tid == 0) { sb1 = 0; sb2 = 0; }
    __syncthreads();
    for (int c0 = 0; c0 < NN; c0 += 1024) {
        int i = c0 + tid;
        int a0 = (i < NN) ? indeg[i] : 0;
        int b0 = (i < NN && ntype[i] == 0) ? 1 : 0;
        int a = a0, b = b0;
#pragma unroll
        for (int off = 1; off < 64; off <<= 1) {
            int ua = __shfl_up(a, off);
            int ub = __shfl_up(b, off);
            if (lane >= off) { a += ua; b += ub; }
        }
        if (lane == 63) { w1[wid] = a; w2[wid] = b; }
        __syncthreads();
        if (wid == 0) {
            int wa = (lane < 16) ? w1[lane] : 0;
            int wb = (lane < 16) ? w2[lane] : 0;
#pragma unroll
            for (int off = 1; off < 16; off <<= 1) {
                int ua = __shfl_up(wa, off);
                int ub = __shfl_up(wb, off);
                if (lane >= off) { wa += ua; wb += ub; }
            }
            if (lane < 16) { w1[lane] = wa; w2[lane] = wb; }
        }
        __syncthreads();
        int ea = sb1 + (wid ? w1[wid - 1] : 0) + (a - a0);
        int eb = sb2 + (wid ? w2[wid - 1] : 0) + (b - b0);
        if (i < NN) { offs[i] = ea; cursor[i] = ea; }
        if (b0 && eb < NDRUG) didx[eb] = i;
        __syncthreads();
        if (tid == 0) { sb1 += w1[15]; sb2 += w2[15]; }
        __syncthreads();
    }
    if (tid == 0) offs[NN] = sb1;
}

__global__ __launch_bounds__(256) void k_scatter(const int* __restrict__ ei,
                                                 const int* __restrict__ et,
                                                 int* __restrict__ cursor,
                                                 int* __restrict__ sorted) {
    int e = blockIdx.x * 256 + threadIdx.x;
    if (e < EE) {
        int dst = ei[EE + e];
        int pos = atomicAdd(&cursor[dst], 1);
        sorted[pos] = ei[e] | (et[e] << 20);
    }
}

// ---------------- prep kernels ----------------

__global__ __launch_bounds__(256) void k_cvt(const float* __restrict__ src,
                                             ushort_t* __restrict__ dst, int n4) {
    int i = blockIdx.x * 256 + threadIdx.x;
    if (i < n4) {
        float4 v = ((const float4*)src)[i];
        uint2 o;
        o.x = (unsigned int)f2bf(v.x) | ((unsigned int)f2bf(v.y) << 16);
        o.y = (unsigned int)f2bf(v.z) | ((unsigned int)f2bf(v.w) << 16);
        ((uint2*)dst)[i] = o;
    }
}

// WcatT[ko][col][e] = bf16(Wcat[k=ko*8+e][col]); slabs 0-7 = W[r], slab 8 = root
__global__ __launch_bounds__(256) void k_prep_wcat(const float* __restrict__ W8,
                                                   const float* __restrict__ root,
                                                   ushort_t* __restrict__ dst) {
    int idx = blockIdx.x * 256 + threadIdx.x;
    if (idx < 144 * 128 * 8) {
        int e = idx & 7, col = (idx >> 3) & 127, ko = idx >> 10;
        int k = ko * 8 + e, slab = k >> 7, kk = k & 127;
        const float* src = (slab < 8) ? (W8 + slab * 16384) : root;
        dst[idx] = f2bf(src[kk * 128 + col]);
    }
}

// MLP weights, [col][kk] layout (staged to LDS by k_mfma_nn)
__global__ __launch_bounds__(256) void k_prep_w(const float* __restrict__ root,
                                                ushort_t* __restrict__ dst) {
    int idx = blockIdx.x * 256 + threadIdx.x;
    if (idx < 16384) {
        int col = idx >> 7, kk = idx & 127;
        dst[idx] = f2bf(root[kk * 128 + col]);
    }
}

// Wb3[ko][o][e] = bf16(bilW[o][kk=ko*8+e])  (coalesced for k_bil lanes)
__global__ __launch_bounds__(256) void k_prep_wb3(const float* __restrict__ bilW,
                                                  ushort_t* __restrict__ dst) {
    int idx = blockIdx.x * 256 + threadIdx.x;
    if (idx < 2097152) {
        int e = idx & 7, o = (idx >> 3) & 127, ko = idx >> 10;
        dst[idx] = f2bf(bilW[(size_t)o * 16384 + ko * 8 + e]);
    }
}

// ---------------- fused RGCN layer ----------------
// h_out = relu( [mean_r(h_in) ... , h_in] @ WcatT + bias )
// 512 thr = 8 waves; 32 nodes/block; gather in regs -> LDS bf16 -> MFMA (K=1152)
__global__ __launch_bounds__(512) void k_layer(const ushort_t* __restrict__ hin,
                                               const ushort_t* __restrict__ WcatT,
                                               const float* __restrict__ bias,
                                               const float* __restrict__ inv,
                                               const int* __restrict__ offs,
                                               const int* __restrict__ sorted,
                                               ushort_t* __restrict__ hout) {
    __shared__ short Af[BML * AFS];
    int tid = threadIdx.x;
    int n0 = blockIdx.x * BML;
    int node = tid >> 4, tsub = tid & 15;
    int n = n0 + node;

    float acc[8][8];
#pragma unroll
    for (int r = 0; r < 8; r++)
#pragma unroll
        for (int q = 0; q < 8; q++) acc[r][q] = 0.f;
    short8v hv = {0, 0, 0, 0, 0, 0, 0, 0};

    if (n < NN) {
        hv = ((const short8v*)hin)[(size_t)n * 16 + tsub];
        int e0 = offs[n], e1 = offs[n + 1];
        for (int e = e0; e < e1; e++) {
            int pk = sorted[e];
            int src = pk & 0xFFFFF;
            int et = pk >> 20;
            union { int4v v; short s[8]; } u;
            u.v = ((const int4v*)hin)[(size_t)src * 16 + tsub];
            float v[8];
#pragma unroll
            for (int q = 0; q < 8; q++) v[q] = bf2f((ushort_t)u.s[q]);
#define CASE_R(R) case R: _Pragma("unroll") for (int q = 0; q < 8; q++) acc[R][q] += v[q]; break;
            switch (et) {
                CASE_R(0) CASE_R(1) CASE_R(2) CASE_R(3)
                CASE_R(4) CASE_R(5) CASE_R(6) CASE_R(7)
            }
#undef CASE_R
        }
    }
    // flush all 9 slabs (zeros for absent relations / tail rows)
    int nc = (n < NN) ? n : (NN - 1);
#pragma unroll
    for (int slab = 0; slab < 8; slab++) {
        float sc = (n < NN) ? inv[nc * 8 + slab] : 0.f;
        union { unsigned int u[4]; short8v v; } cv;
        cv.u[0] = pkbf(acc[slab][0] * sc, acc[slab][1] * sc);
        cv.u[1] = pkbf(acc[slab][2] * sc, acc[slab][3] * sc);
        cv.u[2] = pkbf(acc[slab][4] * sc, acc[slab][5] * sc);
        cv.u[3] = pkbf(acc[slab][6] * sc, acc[slab][7] * sc);
        *(short8v*)&Af[node * AFS + slab * 128 + tsub * 8] = cv.v;
    }
    *(short8v*)&Af[node * AFS + 1024 + tsub * 8] = hv;
    __syncthreads();

    // MFMA: 8 waves; wave -> (row half, col group of 32)
    int wid = tid >> 6, lane = tid & 63, lo = lane & 15, hi = lane >> 4;
    int rhalf = wid & 1, cgrp = wid >> 1;
    int arow = rhalf * 16 + lo;
    f32x4 a0v = {0.f, 0.f, 0.f, 0.f}, a1v = {0.f, 0.f, 0.f, 0.f};
    const int4v* Bg = (const int4v*)WcatT;
#pragma unroll
    for (int kc = 0; kc < 9; kc++) {
#pragma unroll
        for (int s = 0; s < 4; s++) {
            short8v a = *(const short8v*)&Af[arow * AFS + kc * 128 + s * 32 + hi * 8];
            int ko = kc * 16 + s * 4 + hi;
            union { int4v i; short8v s8; } b0, b1;
            b0.i = Bg[ko * 128 + cgrp * 32 + lo];
            b1.i = Bg[ko * 128 + cgrp * 32 + 16 + lo];
            a0v = __builtin_amdgcn_mfma_f32_16x16x32_bf16(a, b0.s8, a0v, 0, 0, 0);
            a1v = __builtin_amdgcn_mfma_f32_16x16x32_bf16(a, b1.s8, a1v, 0, 0, 0);
        }
    }
#pragma unroll
    for (int q = 0; q < 4; q++) {
        int r = n0 + rhalf * 16 + hi * 4 + q;
        if (r < NN) {
            int c = cgrp * 32 + lo;
            float v0 = fmaxf(a0v[q] + bias[c], 0.f);
            float v1 = fmaxf(a1v[q] + bias[c + 16], 0.f);
            hout[(size_t)r * 128 + c] = f2bf(v0);
            hout[(size_t)r * 128 + c + 16] = f2bf(v1);
        }
    }
}

// ---------------- MFMA GEMM (MLP): C = act(A @ Wt + bias) ----------------
__global__ __launch_bounds__(256) void k_mfma_nn(const ushort_t* __restrict__ A,
                                                 const ushort_t* __restrict__ Wt,
                                                 const float* __restrict__ bias,
                                                 ushort_t* __restrict__ outb,
                                                 float* __restrict__ outf,
                                                 int M, int nMblk, int relu) {
    __shared__ short As[64 * 136];
    __shared__ short Bs[128 * 136];
    int tid = threadIdx.x;
    int mblk = blockIdx.x % nMblk;
    int row0 = mblk * 64;

    const int4v* Ag = (const int4v*)A;
    int4v* AsV = (int4v*)As;
    for (int idx = tid; idx < 1024; idx += 256) {
        int row = idx >> 4, ck = idx & 15;
        int grow = row0 + row;
        int4v v = {0, 0, 0, 0};
        if (grow < M) v = Ag[(size_t)grow * 16 + ck];
        AsV[row * 17 + ck] = v;
    }
    const int4v* Wg = (const int4v*)Wt;
    int4v* BsV = (int4v*)Bs;
    for (int idx = tid; idx < 2048; idx += 256) {
        int col = idx >> 4, ck = idx & 15;
        BsV[col * 17 + ck] = Wg[idx];
    }
    __syncthreads();

    int wid = tid >> 6, lane = tid & 63, lo = lane & 15, hi = lane >> 4;
    int wrow0 = wid * 16;
    f32x4 acc[8];
#pragma unroll
    for (int t = 0; t < 8; t++) acc[t] = (f32x4)(0.f);

#pragma unroll
    for (int s = 0; s < 4; ++s) {
        short8v a = *(const short8v*)&As[(wrow0 + lo) * 136 + s * 32 + hi * 8];
#pragma unroll
        for (int t = 0; t < 8; t++) {
            short8v b = *(const short8v*)&Bs[(t * 16 + lo) * 136 + s * 32 + hi * 8];
            acc[t] = __builtin_amdgcn_mfma_f32_16x16x32_bf16(a, b, acc[t], 0, 0, 0);
        }
    }

#pragma unroll
    for (int t = 0; t < 8; t++) {
        int col = t * 16 + lo;
        float bs = bias ? bias[col] : 0.f;
#pragma unroll
        for (int q = 0; q < 4; q++) {
            int grow = row0 + wrow0 + hi * 4 + q;
            if (grow < M) {
                float v = acc[t][q] + bs;
                if (relu) v = fmaxf(v, 0.f);
                size_t oidx = (size_t)grow * 128 + col;
                if (outb) outb[oidx] = f2bf(v);
                else      outf[oidx] = v;
            }
        }
    }
}

// ---------------- bilinear: MFMA with on-the-fly rank-1 A ----------------
__global__ __launch_bounds__(512) void k_bil(const ushort_t* __restrict__ hb,
                                             const int* __restrict__ didx,
                                             const int* __restrict__ efil,
                                             const ushort_t* __restrict__ Wb,
                                             const float* __restrict__ bilb,
                                             ushort_t* __restrict__ xab) {
    __shared__ __align__(16) char smem[65536];
    __shared__ int pa[32], pb[32];
    float* faT = (float*)smem;             // [i:128][33] padded (16-way -> none)
    float* fbF = (float*)(smem + 16896);   // [p:32][j:132] via float4 stride 33
    int tid = threadIdx.x;
    int p0 = blockIdx.x * 32;

    if (tid < 32) pa[tid] = didx[efil[p0 + tid]];
    else if (tid < 64) pb[tid - 32] = didx[efil[PPAIR + p0 + tid - 32]];
    __syncthreads();

    {
        int p = tid >> 4, c8 = tid & 15;
        const int4v* hg = (const int4v*)hb;
        union { int4v v; short s[8]; } ra, rb;
        ra.v = hg[(size_t)pa[p] * 16 + c8];
        rb.v = hg[(size_t)pb[p] * 16 + c8];
        float4* fb4 = (float4*)fbF;
        float4 f0, f1;
        f0.x = bf2f((ushort_t)rb.s[0]); f0.y = bf2f((ushort_t)rb.s[1]);
        f0.z = bf2f((ushort_t)rb.s[2]); f0.w = bf2f((ushort_t)rb.s[3]);
        f1.x = bf2f((ushort_t)rb.s[4]); f1.y = bf2f((ushort_t)rb.s[5]);
        f1.z = bf2f((ushort_t)rb.s[6]); f1.w = bf2f((ushort_t)rb.s[7]);
        fb4[p * 33 + c8 * 2] = f0;
        fb4[p * 33 + c8 * 2 + 1] = f1;
#pragma unroll
        for (int j = 0; j < 8; j++)
            faT[(c8 * 8 + j) * 33 + p] = bf2f((ushort_t)ra.s[j]);
    }
    __syncthreads();

    int wid = tid >> 6, lane = tid & 63, lo = lane & 15, hi = lane >> 4;
    const int4v* Wbg = (const int4v*)Wb;
    const float4* fb4 = (const float4*)fbF;

    f32x4 acc0[8], acc1[8];
#pragma unroll
    for (int t = 0; t < 8; t++) { acc0[t] = (f32x4)(0.f); acc1[t] = (f32x4)(0.f); }

    for (int s = 0; s < 64; ++s) {
        int ko = (wid << 8) + (s << 2) + hi;
        int4v braw[8];
#pragma unroll
        for (int t = 0; t < 8; t++)
            braw[t] = Wbg[ko * 128 + t * 16 + lo];     // 16 lanes contiguous

        int i = (wid << 4) + (s >> 2);
        int jc4 = ((s & 3) << 3) + (hi << 1);
        short8v afr0, afr1;
#pragma unroll
        for (int mi = 0; mi < 2; ++mi) {
            int prow = (mi << 4) + lo;
            float fa = faT[i * 33 + prow];
            float4 f0 = fb4[prow * 33 + jc4];
            float4 f1 = fb4[prow * 33 + jc4 + 1];
            union { unsigned int u[4]; short8v v; } cv;
            cv.u[0] = pkbf(fa * f0.x, fa * f0.y);
            cv.u[1] = pkbf(fa * f0.z, fa * f0.w);
            cv.u[2] = pkbf(fa * f1.x, fa * f1.y);
            cv.u[3] = pkbf(fa * f1.z, fa * f1.w);
            if (mi == 0) afr0 = cv.v; else afr1 = cv.v;
        }
#pragma unroll
        for (int t = 0; t < 8; t++) {
            union { int4v i4; short8v s8; } bb; bb.i4 = braw[t];
            acc0[t] = __builtin_amdgcn_mfma_f32_16x16x32_bf16(afr0, bb.s8, acc0[t], 0, 0, 0);
            acc1[t] = __builtin_amdgcn_mfma_f32_16x16x32_bf16(afr1, bb.s8, acc1[t], 0, 0, 0);
        }
    }
    __syncthreads();   // smem becomes reduce buffer red[4][32][128]

    float* redF = (float*)smem;
    if (wid >= 4) {
        float* r = redF + (wid - 4) * 4096;
#pragma unroll
        for (int t = 0; t < 8; t++)
#pragma unroll
            for (int q = 0; q < 4; q++) {
                r[(hi * 4 + q) * 128 + t * 16 + lo] = acc0[t][q];
                r[(16 + hi * 4 + q) * 128 + t * 16 + lo] = acc1[t][q];
            }
    }
    __syncthreads();
    if (wid < 4) {
        float* r = redF + wid * 4096;
#pragma unroll
        for (int t = 0; t < 8; t++)
#pragma unroll
            for (int q = 0; q < 4; q++) {
                acc0[t][q] += r[(hi * 4 + q) * 128 + t * 16 + lo];
                acc1[t][q] += r[(16 + hi * 4 + q) * 128 + t * 16 + lo];
            }
    }
    __syncthreads();
    if (wid < 4) {
        float* r = redF + wid * 4096;
#pragma unroll
        for (int t = 0; t < 8; t++)
#pragma unroll
            for (int q = 0; q < 4; q++) {
                r[(hi * 4 + q) * 128 + t * 16 + lo] = acc0[t][q];
                r[(16 + hi * 4 + q) * 128 + t * 16 + lo] = acc1[t][q];
            }
    }
    __syncthreads();
    for (int idx = tid; idx < 4096; idx += 512) {
        float s = redF[idx] + redF[4096 + idx] + redF[8192 + idx] + redF[12288 + idx]
                + bilb[idx & 127];
        s = fmaxf(s, 0.f);
        xab[(size_t)(p0 + (idx >> 7)) * 128 + (idx & 127)] = f2bf(s);
    }
}

// ---------------- launch ----------------

extern "C" void kernel_launch(void* const* d_in, const int* in_sizes, int n_in,
                              void* d_out, int out_size, void* d_ws, size_t ws_size,
                              hipStream_t stream) {
    const float* x      = (const float*)d_in[0];
    const int*   ei     = (const int*)d_in[1];
    const int*   et     = (const int*)d_in[2];
    const int*   ntype  = (const int*)d_in[3];
    const int*   efil   = (const int*)d_in[4];
    const float* W1 = (const float*)d_in[5];
    const float* r1 = (const float*)d_in[6];
    const float* b1 = (const float*)d_in[7];
    const float* W2 = (const float*)d_in[8];
    const float* r2 = (const float*)d_in[9];
    const float* b2 = (const float*)d_in[10];
    const float* W3 = (const float*)d_in[11];
    const float* r3 = (const float*)d_in[12];
    const float* b3 = (const float*)d_in[13];
    const float* bilW = (const float*)d_in[14];
    const float* bilb = (const float*)d_in[15];
    const float* m1W = (const float*)d_in[16];
    const float* m1b = (const float*)d_in[17];
    const float* m2W = (const float*)d_in[18];
    const float* m2b = (const float*)d_in[19];
    const float* m3W = (const float*)d_in[20];
    const float* m3b = (const float*)d_in[21];
    float* outp = (float*)d_out;

    char* ws = (char*)d_ws;
    size_t off = 0;
    auto alloc = [&](size_t bytes) { size_t c = off; off = (off + bytes + 255) & ~(size_t)255; return c; };

    size_t oxb   = alloc((size_t)NN * 128 * 2);
    size_t ohA   = alloc((size_t)NN * 128 * 2);
    size_t ohB   = alloc((size_t)NN * 128 * 2);
    size_t oWc1  = alloc((size_t)144 * 128 * 8 * 2);
    size_t oWc2  = alloc((size_t)144 * 128 * 8 * 2);
    size_t oWc3  = alloc((size_t)144 * 128 * 8 * 2);
    size_t omW1  = alloc((size_t)16384 * 2);
    size_t omW2  = alloc((size_t)16384 * 2);
    size_t omW3  = alloc((size_t)16384 * 2);
    size_t oWb   = alloc((size_t)2097152 * 2);
    size_t oxab1 = alloc((size_t)PPAIR * 128 * 2);
    size_t oxab2 = alloc((size_t)PPAIR * 128 * 2);
    size_t ocnt  = alloc((size_t)NN * RRR * sizeof(int));
    size_t oinv  = alloc((size_t)NN * RRR * sizeof(float));
    size_t oindeg = alloc((size_t)NN * sizeof(int));
    size_t ooffs = alloc((size_t)(NN + 1) * sizeof(int));
    size_t ocur  = alloc((size_t)NN * sizeof(int));
    size_t osort = alloc((size_t)EE * sizeof(int));
    size_t odidx = alloc((size_t)NDRUG * sizeof(int));

    ushort_t* xb   = (ushort_t*)(ws + oxb);
    ushort_t* hbA  = (ushort_t*)(ws + ohA);
    ushort_t* hbB  = (ushort_t*)(ws + ohB);
    ushort_t* Wc1  = (ushort_t*)(ws + oWc1);
    ushort_t* Wc2  = (ushort_t*)(ws + oWc2);
    ushort_t* Wc3  = (ushort_t*)(ws + oWc3);
    ushort_t* mWt1 = (ushort_t*)(ws + omW1);
    ushort_t* mWt2 = (ushort_t*)(ws + omW2);
    ushort_t* mWt3 = (ushort_t*)(ws + omW3);
    ushort_t* Wb3  = (ushort_t*)(ws + oWb);
    ushort_t* xab1 = (ushort_t*)(ws + oxab1);
    ushort_t* xab2 = (ushort_t*)(ws + oxab2);
    int*      cnt  = (int*)(ws + ocnt);
    float*    inv  = (float*)(ws + oinv);
    int*      indeg = (int*)(ws + oindeg);
    int*      offs = (int*)(ws + ooffs);
    int*      cursor = (int*)(ws + ocur);
    int*      sorted = (int*)(ws + osort);
    int*      didx = (int*)(ws + odidx);

    hipMemsetAsync(cnt, 0, (size_t)NN * RRR * sizeof(int), stream);
    hipMemsetAsync(didx, 0, (size_t)NDRUG * sizeof(int), stream);

    // prep
    k_cvt<<<(NN * 128 / 4 + 255) / 256, 256, 0, stream>>>(x, xb, NN * 128 / 4);
    k_prep_wcat<<<(144 * 128 * 8 + 255) / 256, 256, 0, stream>>>(W1, r1, Wc1);
    k_prep_wcat<<<(144 * 128 * 8 + 255) / 256, 256, 0, stream>>>(W2, r2, Wc2);
    k_prep_wcat<<<(144 * 128 * 8 + 255) / 256, 256, 0, stream>>>(W3, r3, Wc3);
    k_prep_w<<<(16384 + 255) / 256, 256, 0, stream>>>(m1W, mWt1);
    k_prep_w<<<(16384 + 255) / 256, 256, 0, stream>>>(m2W, mWt2);
    k_prep_w<<<(16384 + 255) / 256, 256, 0, stream>>>(m3W, mWt3);
    k_prep_wb3<<<(2097152 + 255) / 256, 256, 0, stream>>>(bilW, Wb3);

    // graph setup
    k_count<<<(EE + 255) / 256, 256, 0, stream>>>(ei, et, cnt);
    k_inv_indeg<<<(NN + 255) / 256, 256, 0, stream>>>(cnt, inv, indeg);
    k_scan_sel<<<1, 1024, 0, stream>>>(indeg, ntype, offs, cursor, didx);
    k_scatter<<<(EE + 255) / 256, 256, 0, stream>>>(ei, et, cursor, sorted);

    const int NBL = (NN + BML - 1) / BML;

    // fused RGCN layers
    k_layer<<<NBL, 512, 0, stream>>>(xb,  Wc1, b1, inv, offs, sorted, hbA);
    k_layer<<<NBL, 512, 0, stream>>>(hbA, Wc2, b2, inv, offs, sorted, hbB);
    k_layer<<<NBL, 512, 0, stream>>>(hbB, Wc3, b3, inv, offs, sorted, hbA);

    // pair head
    k_bil<<<PPAIR / 32, 512, 0, stream>>>(hbA, didx, efil, Wb3, bilb, xab1);
    const int nMblkP = PPAIR / 64;
    k_mfma_nn<<<nMblkP, 256, 0, stream>>>(xab1, mWt1, m1b, xab2, nullptr, PPAIR, nMblkP, 1);
    k_mfma_nn<<<nMblkP, 256, 0, stream>>>(xab2, mWt2, m2b, xab1, nullptr, PPAIR, nMblkP, 1);
    k_mfma_nn<<<nMblkP, 256, 0, stream>>>(xab1, mWt3, m3b, nullptr, outp, PPAIR, nMblkP, 0);
}